// Round 5
// baseline (511.911 us; speedup 1.0000x reference)
//
#include <hip/hip_runtime.h>
#include <math.h>

#define Bdim 256
#define Ndim 4096
#define Mdim 64
#define EPSF 1e-16f

typedef float vf4 __attribute__((ext_vector_type(4)));

// ---------------------------------------------------------------------------
// Fully fused NTM memory step: one block per batch (256 blocks x 1024 thr).
// Phase 1: stream mem[b] (1 MB) -> q[4096] in LDS   (cos numer/denominator)
// Phase 2: softmax(beta*cos) -> gate -> circular conv -> pow -> normalize (LDS)
// Phase 3: re-stream mem[b] IN REVERSE (stack-order: own tail is hottest in
//          L2/L3) -> rd (in-block tree reduce, no atomics) + new_mem (NT
//          stores: don't let the 256 MiB write stream evict read lines).
// No cross-block communication: each batch is independent.
// ---------------------------------------------------------------------------
__device__ __forceinline__ float block_reduce_sum16(float v, float* red, int t)
{
    const int lane = t & 63, wave = t >> 6;
    #pragma unroll
    for (int mask = 32; mask; mask >>= 1) v += __shfl_xor(v, mask);
    __syncthreads();                 // protect red[] reuse across calls
    if (lane == 0) red[wave] = v;
    __syncthreads();
    float sum = 0.f;
    #pragma unroll
    for (int i = 0; i < 16; ++i) sum += red[i];
    return sum;
}

__device__ __forceinline__ float block_reduce_max16(float v, float* red, int t)
{
    const int lane = t & 63, wave = t >> 6;
    #pragma unroll
    for (int mask = 32; mask; mask >>= 1) v = fmaxf(v, __shfl_xor(v, mask));
    __syncthreads();
    if (lane == 0) red[wave] = v;
    __syncthreads();
    float m = red[0];
    #pragma unroll
    for (int i = 1; i < 16; ++i) m = fmaxf(m, red[i]);
    return m;
}

__global__ __launch_bounds__(1024) void ntm_fused_kernel(
    const float* __restrict__ mem, const float* __restrict__ k,
    const float* __restrict__ beta, const float* __restrict__ g,
    const float* __restrict__ s, const float* __restrict__ gamma,
    const float* __restrict__ w_prev, const float* __restrict__ e,
    const float* __restrict__ a,
    float* __restrict__ rd, float* __restrict__ new_mem,
    float* __restrict__ w_out)
{
    __shared__ float q_lds[Ndim];          // 16 KB: cos*||k|| per row
    __shared__ float w_lds[Ndim];          // 16 KB: wg, then w
    __shared__ float red[16];
    __shared__ vf4   redc[16][16];         // 4 KB: rd partials
    __shared__ float sh_kn;

    const int b = blockIdx.x;
    const int t = threadIdx.x;             // 0..1023
    const int m4 = t & 15;                 // float4 column index
    const int rsub = t >> 4;               // 0..63: row within a sweep
    const int lane = t & 63, wave = t >> 6;

    // k norm (factored out of cos; folded into beta_eff)
    if (wave == 0) {
        float v = k[b * Mdim + lane] + EPSF;
        float sq = v * v;
        #pragma unroll
        for (int mask = 32; mask; mask >>= 1) sq += __shfl_xor(sq, mask);
        if (lane == 0) sh_kn = fmaxf(sqrtf(sq), 1e-8f);
    }

    float4 ke = reinterpret_cast<const float4*>(k + b * Mdim)[m4];
    ke.x += EPSF; ke.y += EPSF; ke.z += EPSF; ke.w += EPSF;

    const vf4* memb = reinterpret_cast<const vf4*>(mem + (size_t)b * Ndim * Mdim);

    // ---- Phase 1: q[row] = dot(mem+eps,k+eps)/max(||mem+eps||,1e-8) ----
    #pragma unroll 4
    for (int sweep = 0; sweep < Ndim / 64; ++sweep) {      // 64 sweeps, ascending
        const int row = sweep * 64 + rsub;
        vf4 mv = memb[row * 16 + m4];
        mv += EPSF;
        float d  = mv.x * ke.x + mv.y * ke.y + mv.z * ke.z + mv.w * ke.w;
        float nr = mv.x * mv.x + mv.y * mv.y + mv.z * mv.z + mv.w * mv.w;
        #pragma unroll
        for (int mask = 1; mask < 16; mask <<= 1) {
            d  += __shfl_xor(d, mask);
            nr += __shfl_xor(nr, mask);
        }
        if (m4 == 0) q_lds[row] = d / fmaxf(sqrtf(nr), 1e-8f);
    }
    __syncthreads();

    // ---- Phase 2: softmax / gate / conv / sharpen (each thread owns n=4t..4t+3)
    const float beta_eff = beta[b] / sh_kn;
    const float gb = g[b];
    const float s0 = s[b * 3 + 0], s1 = s[b * 3 + 1], s2 = s[b * 3 + 2];
    const float gam = gamma[b];

    vf4 z = reinterpret_cast<const vf4*>(q_lds)[t] * beta_eff;
    float zmax = fmaxf(fmaxf(z.x, z.y), fmaxf(z.z, z.w));
    zmax = block_reduce_max16(zmax, red, t);

    z.x = expf(z.x - zmax); z.y = expf(z.y - zmax);
    z.z = expf(z.z - zmax); z.w = expf(z.w - zmax);
    float esum = z.x + z.y + z.z + z.w;
    esum = block_reduce_sum16(esum, red, t);
    const float inv_esum = 1.0f / esum;

    const float4 wp4 = reinterpret_cast<const float4*>(w_prev + (size_t)b * Ndim)[t];
    vf4 wg;
    wg.x = gb * (z.x * inv_esum) + (1.f - gb) * wp4.x;
    wg.y = gb * (z.y * inv_esum) + (1.f - gb) * wp4.y;
    wg.z = gb * (z.z * inv_esum) + (1.f - gb) * wp4.z;
    wg.w = gb * (z.w * inv_esum) + (1.f - gb) * wp4.w;
    reinterpret_cast<vf4*>(w_lds)[t] = wg;
    __syncthreads();

    // circular 3-tap conv + sharpen
    const int n0 = 4 * t;
    const float left  = w_lds[(n0 + Ndim - 1) & (Ndim - 1)];
    const float right = w_lds[(n0 + 4) & (Ndim - 1)];
    vf4 h;
    h.x = s0 * left + s1 * wg.x + s2 * wg.y;
    h.y = s0 * wg.x + s1 * wg.y + s2 * wg.z;
    h.z = s0 * wg.y + s1 * wg.z + s2 * wg.w;
    h.w = s0 * wg.z + s1 * wg.w + s2 * right;
    h.x = powf(h.x, gam); h.y = powf(h.y, gam);
    h.z = powf(h.z, gam); h.w = powf(h.w, gam);
    float psum = h.x + h.y + h.z + h.w;
    psum = block_reduce_sum16(psum, red, t);   // internal syncs also fence w_lds reads
    const float inv_psum = 1.0f / (psum + EPSF);
    h *= inv_psum;

    reinterpret_cast<vf4*>(w_lds)[t] = h;                                    // w for phase 3
    reinterpret_cast<vf4*>(w_out + (size_t)b * Ndim)[t] = h;                 // w output
    __syncthreads();

    // ---- Phase 3: rd += w[n]*mem[n,:], new_mem = mem*(1-w*e)+w*a ----
    // Reverse sweep order: the block's own tail lines are most-recently-cached.
    const float4 ev4 = reinterpret_cast<const float4*>(e + b * Mdim)[m4];
    const float4 av4 = reinterpret_cast<const float4*>(a + b * Mdim)[m4];
    const vf4 ev = {ev4.x, ev4.y, ev4.z, ev4.w};
    const vf4 av = {av4.x, av4.y, av4.z, av4.w};
    vf4* nmb = reinterpret_cast<vf4*>(new_mem + (size_t)b * Ndim * Mdim);

    vf4 acc = {0.f, 0.f, 0.f, 0.f};
    #pragma unroll 4
    for (int s2i = 0; s2i < Ndim / 64; ++s2i) {
        const int sweep = (Ndim / 64 - 1) - s2i;           // descending
        const int row = sweep * 64 + rsub;
        const float wr = w_lds[row];
        vf4 mv = memb[row * 16 + m4];
        acc += wr * mv;
        vf4 nm = mv * (1.f - wr * ev) + wr * av;
        __builtin_nontemporal_store(nm, &nmb[row * 16 + m4]);
    }

    // rd reduce: lanes {l, l^16, l^32, l^48} share column group m4
    #pragma unroll
    for (int mask = 16; mask <= 32; mask <<= 1) {
        acc.x += __shfl_xor(acc.x, mask);
        acc.y += __shfl_xor(acc.y, mask);
        acc.z += __shfl_xor(acc.z, mask);
        acc.w += __shfl_xor(acc.w, mask);
    }
    if (lane < 16) redc[wave][lane] = acc;
    __syncthreads();

    if (t < 16) {
        vf4 tot = redc[0][t];
        #pragma unroll
        for (int wv = 1; wv < 16; ++wv) tot += redc[wv][t];
        reinterpret_cast<vf4*>(rd + b * Mdim)[t] = tot;    // direct store, no atomics
    }
}

// ---------------------------------------------------------------------------
extern "C" void kernel_launch(void* const* d_in, const int* in_sizes, int n_in,
                              void* d_out, int out_size, void* d_ws, size_t ws_size,
                              hipStream_t stream)
{
    const float* mem    = (const float*)d_in[0];
    const float* k      = (const float*)d_in[1];
    const float* beta   = (const float*)d_in[2];
    const float* g      = (const float*)d_in[3];
    const float* s      = (const float*)d_in[4];
    const float* gamma  = (const float*)d_in[5];
    const float* w_prev = (const float*)d_in[6];
    const float* e      = (const float*)d_in[7];
    const float* a      = (const float*)d_in[8];

    float* out     = (float*)d_out;
    float* rd      = out;                                   // [B, M]
    float* new_mem = out + Bdim * Mdim;                     // [B, N, M]
    float* w_out   = out + Bdim * Mdim + (size_t)Bdim * Ndim * Mdim; // [B, N]

    ntm_fused_kernel<<<Bdim, 1024, 0, stream>>>(
        mem, k, beta, g, s, gamma, w_prev, e, a, rd, new_mem, w_out);
}

// Round 6
// 511.691 us; speedup vs baseline: 1.0004x; 1.0004x over previous
//
#include <hip/hip_runtime.h>
#include <math.h>

#define Bdim 256
#define Ndim 4096
#define Mdim 64
#define EPSF 1e-16f

typedef float vf4 __attribute__((ext_vector_type(4)));

// ---------------------------------------------------------------------------
// Fully fused NTM memory step: one block per batch (256 blocks x 1024 thr).
// R5 counters: traffic is at floor (FETCH 262 MB = one memory read; phase-3
// re-read 100% cache-served thanks to per-block reverse + NT stores), but BW
// util was 33% -- latency-bound (VGPR=36, no load batching, 16 waves/CU).
// R6 change: explicit 8-deep load batching in phases 1 & 3 (MLP), fast
// HW transcendentals in phase 2, hoisted small loads.
// ---------------------------------------------------------------------------
__device__ __forceinline__ float block_reduce_sum16(float v, float* red, int t)
{
    const int lane = t & 63, wave = t >> 6;
    #pragma unroll
    for (int mask = 32; mask; mask >>= 1) v += __shfl_xor(v, mask);
    __syncthreads();                 // protect red[] reuse across calls
    if (lane == 0) red[wave] = v;
    __syncthreads();
    float sum = 0.f;
    #pragma unroll
    for (int i = 0; i < 16; ++i) sum += red[i];
    return sum;
}

__device__ __forceinline__ float block_reduce_max16(float v, float* red, int t)
{
    const int lane = t & 63, wave = t >> 6;
    #pragma unroll
    for (int mask = 32; mask; mask >>= 1) v = fmaxf(v, __shfl_xor(v, mask));
    __syncthreads();
    if (lane == 0) red[wave] = v;
    __syncthreads();
    float m = red[0];
    #pragma unroll
    for (int i = 1; i < 16; ++i) m = fmaxf(m, red[i]);
    return m;
}

__global__ __launch_bounds__(1024) void ntm_fused_kernel(
    const float* __restrict__ mem, const float* __restrict__ k,
    const float* __restrict__ beta, const float* __restrict__ g,
    const float* __restrict__ s, const float* __restrict__ gamma,
    const float* __restrict__ w_prev, const float* __restrict__ e,
    const float* __restrict__ a,
    float* __restrict__ rd, float* __restrict__ new_mem,
    float* __restrict__ w_out)
{
    __shared__ float q_lds[Ndim];          // 16 KB
    __shared__ float w_lds[Ndim];          // 16 KB
    __shared__ float red[16];
    __shared__ vf4   redc[16][16];         // 4 KB
    __shared__ float sh_kn;

    const int b = blockIdx.x;
    const int t = threadIdx.x;             // 0..1023
    const int m4 = t & 15;                 // float4 column index
    const int rsub = t >> 4;               // 0..63: row within a sweep
    const int lane = t & 63, wave = t >> 6;

    // ---- hoisted small loads (latency hidden under phase 1) ----
    float4 ke = reinterpret_cast<const float4*>(k + b * Mdim)[m4];
    const float4 wp4 = reinterpret_cast<const float4*>(w_prev + (size_t)b * Ndim)[t];
    const float4 ev4 = reinterpret_cast<const float4*>(e + b * Mdim)[m4];
    const float4 av4 = reinterpret_cast<const float4*>(a + b * Mdim)[m4];
    const float beta_b = beta[b], gb = g[b], gam = gamma[b];
    const float s0 = s[b * 3 + 0], s1 = s[b * 3 + 1], s2 = s[b * 3 + 2];

    // k norm (factored out of cos; folded into beta_eff)
    if (wave == 0) {
        float v = k[b * Mdim + lane] + EPSF;
        float sq = v * v;
        #pragma unroll
        for (int mask = 32; mask; mask >>= 1) sq += __shfl_xor(sq, mask);
        if (lane == 0) sh_kn = fmaxf(sqrtf(sq), 1e-8f);
    }

    ke.x += EPSF; ke.y += EPSF; ke.z += EPSF; ke.w += EPSF;

    const vf4* memb = reinterpret_cast<const vf4*>(mem + (size_t)b * Ndim * Mdim);

    // ---- Phase 1: q[row] = dot(mem+eps,k+eps)/max(||mem+eps||,1e-8) ----
    // 8 batches of 8 sweeps: 8 loads issued back-to-back (8x16B in flight per
    // lane), then 8 shuffle-reduce trees consume them.
    for (int big = 0; big < 8; ++big) {
        vf4 mv[8];
        #pragma unroll
        for (int j = 0; j < 8; ++j) {
            const int row = (big * 8 + j) * 64 + rsub;
            mv[j] = memb[row * 16 + m4];
        }
        #pragma unroll
        for (int j = 0; j < 8; ++j) {
            const int row = (big * 8 + j) * 64 + rsub;
            vf4 m = mv[j] + EPSF;
            float d  = m.x * ke.x + m.y * ke.y + m.z * ke.z + m.w * ke.w;
            float nr = m.x * m.x + m.y * m.y + m.z * m.z + m.w * m.w;
            #pragma unroll
            for (int mask = 1; mask < 16; mask <<= 1) {
                d  += __shfl_xor(d, mask);
                nr += __shfl_xor(nr, mask);
            }
            if (m4 == 0) q_lds[row] = d / fmaxf(sqrtf(nr), 1e-8f);
        }
    }
    __syncthreads();

    // ---- Phase 2: softmax / gate / conv / sharpen (thread owns n=4t..4t+3) ----
    const float beta_eff = beta_b / sh_kn;

    vf4 z = reinterpret_cast<const vf4*>(q_lds)[t] * beta_eff;
    float zmax = fmaxf(fmaxf(z.x, z.y), fmaxf(z.z, z.w));
    zmax = block_reduce_max16(zmax, red, t);

    z.x = __expf(z.x - zmax); z.y = __expf(z.y - zmax);
    z.z = __expf(z.z - zmax); z.w = __expf(z.w - zmax);
    float esum = z.x + z.y + z.z + z.w;
    esum = block_reduce_sum16(esum, red, t);
    const float inv_esum = 1.0f / esum;

    vf4 wg;
    wg.x = gb * (z.x * inv_esum) + (1.f - gb) * wp4.x;
    wg.y = gb * (z.y * inv_esum) + (1.f - gb) * wp4.y;
    wg.z = gb * (z.z * inv_esum) + (1.f - gb) * wp4.z;
    wg.w = gb * (z.w * inv_esum) + (1.f - gb) * wp4.w;
    reinterpret_cast<vf4*>(w_lds)[t] = wg;
    __syncthreads();

    // circular 3-tap conv + sharpen (h > 0 strictly: softmax-derived)
    const int n0 = 4 * t;
    const float left  = w_lds[(n0 + Ndim - 1) & (Ndim - 1)];
    const float right = w_lds[(n0 + 4) & (Ndim - 1)];
    vf4 h;
    h.x = s0 * left + s1 * wg.x + s2 * wg.y;
    h.y = s0 * wg.x + s1 * wg.y + s2 * wg.z;
    h.z = s0 * wg.y + s1 * wg.z + s2 * wg.w;
    h.w = s0 * wg.z + s1 * wg.w + s2 * right;
    h.x = __powf(h.x, gam); h.y = __powf(h.y, gam);
    h.z = __powf(h.z, gam); h.w = __powf(h.w, gam);
    float psum = h.x + h.y + h.z + h.w;
    psum = block_reduce_sum16(psum, red, t);   // internal syncs fence w_lds reads
    const float inv_psum = 1.0f / (psum + EPSF);
    h *= inv_psum;

    reinterpret_cast<vf4*>(w_lds)[t] = h;                                    // w for phase 3
    reinterpret_cast<vf4*>(w_out + (size_t)b * Ndim)[t] = h;                 // w output
    __syncthreads();

    // ---- Phase 3: rd += w[n]*mem[n,:], new_mem = mem*(1-w*e)+w*a ----
    // Reverse sweep order (stack order: own tail lines hottest in L3).
    // Same 8-deep load batching; NT stores keep the write stream out of L3.
    const vf4 ev = {ev4.x, ev4.y, ev4.z, ev4.w};
    const vf4 av = {av4.x, av4.y, av4.z, av4.w};
    vf4* nmb = reinterpret_cast<vf4*>(new_mem + (size_t)b * Ndim * Mdim);

    vf4 acc = {0.f, 0.f, 0.f, 0.f};
    for (int big = 0; big < 8; ++big) {
        vf4 mv[8];
        float wr[8];
        #pragma unroll
        for (int j = 0; j < 8; ++j) {
            const int row = (63 - (big * 8 + j)) * 64 + rsub;
            mv[j] = memb[row * 16 + m4];
            wr[j] = w_lds[row];
        }
        #pragma unroll
        for (int j = 0; j < 8; ++j) {
            const int row = (63 - (big * 8 + j)) * 64 + rsub;
            acc += wr[j] * mv[j];
            vf4 nm = mv[j] * (1.f - wr[j] * ev) + wr[j] * av;
            __builtin_nontemporal_store(nm, &nmb[row * 16 + m4]);
        }
    }

    // rd reduce: lanes {l, l^16, l^32, l^48} share column group m4
    #pragma unroll
    for (int mask = 16; mask <= 32; mask <<= 1) {
        acc.x += __shfl_xor(acc.x, mask);
        acc.y += __shfl_xor(acc.y, mask);
        acc.z += __shfl_xor(acc.z, mask);
        acc.w += __shfl_xor(acc.w, mask);
    }
    if (lane < 16) redc[wave][lane] = acc;
    __syncthreads();

    if (t < 16) {
        vf4 tot = redc[0][t];
        #pragma unroll
        for (int wv = 1; wv < 16; ++wv) tot += redc[wv][t];
        reinterpret_cast<vf4*>(rd + b * Mdim)[t] = tot;    // direct store, no atomics
    }
}

// ---------------------------------------------------------------------------
extern "C" void kernel_launch(void* const* d_in, const int* in_sizes, int n_in,
                              void* d_out, int out_size, void* d_ws, size_t ws_size,
                              hipStream_t stream)
{
    const float* mem    = (const float*)d_in[0];
    const float* k      = (const float*)d_in[1];
    const float* beta   = (const float*)d_in[2];
    const float* g      = (const float*)d_in[3];
    const float* s      = (const float*)d_in[4];
    const float* gamma  = (const float*)d_in[5];
    const float* w_prev = (const float*)d_in[6];
    const float* e      = (const float*)d_in[7];
    const float* a      = (const float*)d_in[8];

    float* out     = (float*)d_out;
    float* rd      = out;                                   // [B, M]
    float* new_mem = out + Bdim * Mdim;                     // [B, N, M]
    float* w_out   = out + Bdim * Mdim + (size_t)Bdim * Ndim * Mdim; // [B, N]

    ntm_fused_kernel<<<Bdim, 1024, 0, stream>>>(
        mem, k, beta, g, s, gamma, w_prev, e, a, rd, new_mem, w_out);
}